// Round 6
// baseline (296.701 us; speedup 1.0000x reference)
//
#include <hip/hip_runtime.h>
#include <cstdint>

#define NANCHOR 33600
#define BATCH   8
#define MGT     32
#define NCLS    80
#define MAXFG   (BATCH * MGT * 10)   // 2560

// ---------------------------------------------------------------------------
// Anchor geometry: levels are [160x160 stride 8 | 80x80 stride 16 | 40x40 stride 32]
// p layout per level: [B, 144, H, W]; channel stride = H*W; anchor n = y*W + x.
// ---------------------------------------------------------------------------
struct AInfo {
    const float* ch0;   // &p_level[b][0][n]  (add c*hw for channel c)
    int   hw;
    float apx, apy, st;
};

__device__ __forceinline__ AInfo anchor_info(const float* p0, const float* p1,
                                             const float* p2, int b, int n) {
    AInfo r;
    if (n < 25600) {
        int nn = n;
        r.ch0 = p0 + (size_t)b * (144 * 25600) + nn;
        r.hw = 25600; r.st = 8.f;
        r.apx = (float)(nn % 160) + 0.5f;
        r.apy = (float)(nn / 160) + 0.5f;
    } else if (n < 32000) {
        int nn = n - 25600;
        r.ch0 = p1 + (size_t)b * (144 * 6400) + nn;
        r.hw = 6400; r.st = 16.f;
        r.apx = (float)(nn % 80) + 0.5f;
        r.apy = (float)(nn / 80) + 0.5f;
    } else {
        int nn = n - 32000;
        r.ch0 = p2 + (size_t)b * (144 * 1600) + nn;
        r.hw = 1600; r.st = 32.f;
        r.apx = (float)(nn % 40) + 0.5f;
        r.apy = (float)(nn / 40) + 0.5f;
    }
    return r;
}

__device__ __forceinline__ float ciou_f(float b1x1, float b1y1, float b1x2, float b1y2,
                                        float g1x, float g1y, float g2x, float g2y) {
    const float eps = 1e-7f;
    float w1 = b1x2 - b1x1, h1 = b1y2 - b1y1;
    float w2 = g2x - g1x,   h2 = g2y - g1y;
    float iw = fminf(b1x2, g2x) - fmaxf(b1x1, g1x);
    float ih = fminf(b1y2, g2y) - fmaxf(b1y1, g1y);
    float inter = fmaxf(iw, 0.f) * fmaxf(ih, 0.f);
    float uni = w1 * h1 + w2 * h2 - inter + eps;
    float iou = inter / uni;
    float cw = fmaxf(b1x2, g2x) - fminf(b1x1, g1x);
    float ch = fmaxf(b1y2, g2y) - fminf(b1y1, g1y);
    float c2 = cw * cw + ch * ch + eps;
    float dx = g1x + g2x - b1x1 - b1x2;
    float dy = g1y + g2y - b1y1 - b1y2;
    float rho2 = (dx * dx + dy * dy) * 0.25f;
    float t = atanf(w2 / (h2 + eps)) - atanf(w1 / (h1 + eps));
    float v = 0.40528473456935108577f * t * t;          // 4/pi^2
    float alpha = v / (v - iou + (1.f + eps));
    return iou - (rho2 / c2 + v * alpha);
}

__device__ __forceinline__ float4 max4(float4 a, float4 b) {
    return make_float4(fmaxf(a.x, b.x), fmaxf(a.y, b.y), fmaxf(a.z, b.z), fmaxf(a.w, b.w));
}
__device__ __forceinline__ float fast_splus(float x) {
    // softplus = max(x,0) + log(1 + e^{-|x|}) via native v_exp/v_log
    return fmaxf(x, 0.f) + __logf(1.f + __expf(-fabsf(x)));
}

// ---------------------------------------------------------------------------
// ws layout:
//   best : unsigned long long [B*N]   packed (score_bits<<32)|(31-m); 0 == no fg
//   pb SoA: px1,py1,px2,py2 float[B*N] each (decoded boxes, image units)
//   acc  : float [256]
//     [b*8+1]=box, +2=dfl, +3=clspos, +4=numfg; ((uint*)acc)[63]=fg-list count
//     [64 + b*8 + j] = softplus partial (j = 0..7)
//   fglist : uint2 [MAXFG]            (bn = b*NANCHOR+n, m)
// ---------------------------------------------------------------------------

__global__ void k_init(float* acc) {
    acc[threadIdx.x] = 0.f;     // 256 threads clear the whole acc region
}

// grid (33, BATCH, 12), block 256.
// roles 0..3 : DFL side `role` (16 channels), one thread = 4 consecutive
//              anchors; writes one coalesced float4 to its SoA plane.
//              role 0 also clears best[].
// roles 4..11: flat softplus streaming over the contiguous cls region
//              (channels 64..143 of each level), grid-stride over 672000 f4.
__global__ __launch_bounds__(256) void k_decode(const float* __restrict__ p0,
                                                const float* __restrict__ p1,
                                                const float* __restrict__ p2,
                                                float4* __restrict__ px1,
                                                float4* __restrict__ py1,
                                                float4* __restrict__ px2,
                                                float4* __restrict__ py2,
                                                unsigned long long* __restrict__ best,
                                                float* __restrict__ acc) {
    int b = blockIdx.y;
    int role = blockIdx.z;
    int tid = threadIdx.x;

    if (role >= 4) {
        int sp_role = role - 4;
        const float4* pc0 = (const float4*)(p0 + (size_t)b * 3686400 + 1638400);
        const float4* pc1 = (const float4*)(p1 + (size_t)b * 921600  + 409600);
        const float4* pc2 = (const float4*)(p2 + (size_t)b * 230400  + 102400);
        float sp = 0.f;
        // 512000 f4 (lvl0) + 128000 (lvl1) + 32000 (lvl2) = 672000
        for (int g = (sp_role * 33 + blockIdx.x) * 256 + tid; g < 672000; g += 67584) {
            float4 x;
            if (g < 512000)      x = pc0[g];
            else if (g < 640000) x = pc1[g - 512000];
            else                 x = pc2[g - 640000];
            sp += fast_splus(x.x) + fast_splus(x.y) + fast_splus(x.z) + fast_splus(x.w);
        }
#pragma unroll
        for (int o = 32; o > 0; o >>= 1) sp += __shfl_down(sp, o, 64);
        if ((tid & 63) == 0) atomicAdd(&acc[64 + b * 8 + sp_role], sp);
        return;
    }

    int t = blockIdx.x * 256 + tid;
    if (t >= NANCHOR / 4) return;
    int n = t * 4;
    const float* ch0; int hw; float st, apx, apy;
    if (n < 25600) {
        ch0 = p0 + (size_t)b * (144 * 25600) + n;
        hw = 25600; st = 8.f;
        apx = (float)(n % 160) + 0.5f; apy = (float)(n / 160) + 0.5f;
    } else if (n < 32000) {
        int nn = n - 25600;
        ch0 = p1 + (size_t)b * (144 * 6400) + nn;
        hw = 6400; st = 16.f;
        apx = (float)(nn % 80) + 0.5f; apy = (float)(nn / 80) + 0.5f;
    } else {
        int nn = n - 32000;
        ch0 = p2 + (size_t)b * (144 * 1600) + nn;
        hw = 1600; st = 32.f;
        apx = (float)(nn % 40) + 0.5f; apy = (float)(nn / 40) + 0.5f;
    }

    const float* side = ch0 + (size_t)(role * 16) * hw;
    float4 v[16];
#pragma unroll
    for (int r = 0; r < 16; r++)
        v[r] = *(const float4*)(side + (size_t)r * hw);
    float4 mx = v[0];
#pragma unroll
    for (int r = 1; r < 16; r++) mx = max4(mx, v[r]);
    float4 s  = make_float4(0.f, 0.f, 0.f, 0.f);
    float4 sw = make_float4(0.f, 0.f, 0.f, 0.f);
#pragma unroll
    for (int r = 0; r < 16; r++) {
        float fr = (float)r;
        float ex = __expf(v[r].x - mx.x);
        float ey = __expf(v[r].y - mx.y);
        float ez = __expf(v[r].z - mx.z);
        float ew = __expf(v[r].w - mx.w);
        s.x += ex; s.y += ey; s.z += ez; s.w += ew;
        sw.x += ex * fr; sw.y += ey * fr; sw.z += ez * fr; sw.w += ew * fr;
    }
    float d0 = sw.x / s.x, d1 = sw.y / s.y, d2 = sw.z / s.z, d3 = sw.w / s.w;

    float4 res;
    if (role == 0)      res = make_float4((apx + 0.f - d0) * st, (apx + 1.f - d1) * st,
                                          (apx + 2.f - d2) * st, (apx + 3.f - d3) * st);
    else if (role == 1) res = make_float4((apy - d0) * st, (apy - d1) * st,
                                          (apy - d2) * st, (apy - d3) * st);
    else if (role == 2) res = make_float4((apx + 0.f + d0) * st, (apx + 1.f + d1) * st,
                                          (apx + 2.f + d2) * st, (apx + 3.f + d3) * st);
    else                res = make_float4((apy + d0) * st, (apy + d1) * st,
                                          (apy + d2) * st, (apy + d3) * st);

    size_t gi = ((size_t)b * NANCHOR + n) >> 2;
    float4* dst = (role == 0) ? px1 : (role == 1) ? py1 : (role == 2) ? px2 : py2;
    dst[gi] = res;

    if (role == 0) {
        // clear fg table for k_assign (runs strictly after this kernel)
        ulonglong2* bq = (ulonglong2*)(best + (size_t)b * NANCHOR + n);
        bq[0] = make_ulonglong2(0ull, 0ull);
        bq[1] = make_ulonglong2(0ull, 0ull);
    }
}

// One block per (b, m). Scans only the per-level index window covering the GT
// box (conservative ±1; exact float in-gt test inside). Selection semantics
// are order-independent: (align value desc, anchor index asc).
// Selected anchors are appended to the compact fg list for k_final.
__global__ __launch_bounds__(256) void k_assign(const float* __restrict__ p0,
                                                const float* __restrict__ p1,
                                                const float* __restrict__ p2,
                                                const float* __restrict__ px1,
                                                const float* __restrict__ py1,
                                                const float* __restrict__ px2,
                                                const float* __restrict__ py2,
                                                const float* __restrict__ gtb,
                                                const int* __restrict__ gtl,
                                                unsigned long long* __restrict__ best,
                                                float* __restrict__ acc,
                                                uint2* __restrict__ fglist) {
    int bm = blockIdx.x;          // 256 blocks: one per (b, m)
    int b = bm >> 5, m = bm & 31;
    const float* g = gtb + (size_t)(b * MGT + m) * 4;
    float g0 = g[0], g1 = g[1], g2 = g[2], g3 = g[3];
    int label = gtl[b * MGT + m];
    int tid = threadIdx.x;

    float tv[10];
    int   ti[10];
#pragma unroll
    for (int j = 0; j < 10; j++) { tv[j] = -1.f; ti[j] = 0x7fffffff; }
    float maxu = 0.f;   // max over UNMASKED align (pre iou>0.1 filter)

    const int   LW[3]   = {160, 80, 40};
    const int   LOFF[3] = {0, 25600, 32000};
    const float LST[3]  = {8.f, 16.f, 32.f};

    for (int l = 0; l < 3; l++) {
        float st = LST[l];
        int W = LW[l];
        float inv_st = 1.f / st;
        int ix0 = max(0,     (int)floorf(g0 * inv_st - 0.5f) - 1);
        int ix1 = min(W - 1, (int)ceilf (g2 * inv_st - 0.5f) + 1);
        int iy0 = max(0,     (int)floorf(g1 * inv_st - 0.5f) - 1);
        int iy1 = min(W - 1, (int)ceilf (g3 * inv_st - 0.5f) + 1);
        int nx = ix1 - ix0 + 1, ny = iy1 - iy0 + 1;
        if (nx <= 0 || ny <= 0) continue;
        int cnt = nx * ny;
        const float* lp = (l == 0) ? p0 : (l == 1) ? p1 : p2;
        int hw = W * W;
        const float* ch0 = lp + (size_t)b * 144 * hw;
        const float* pcls = ch0 + (size_t)(64 + label) * hw;

        for (int idx = tid; idx < cnt; idx += 256) {
            int iy = iy0 + idx / nx;
            int ix = ix0 + idx % nx;
            float ax = ((float)ix + 0.5f) * st;
            float ay = ((float)iy + 0.5f) * st;
            if (ax < g0 || ax > g2 || ay < g1 || ay > g3) continue;   // exact in_gt
            int nn = iy * W + ix;
            int n = LOFF[l] + nn;
            size_t bn = (size_t)b * NANCHOR + n;
            float c = ciou_f(px1[bn], py1[bn], px2[bn], py2[bn], g0, g1, g2, g3);
            float iou = fmaxf(c, 0.f);
            if (iou <= 0.f) continue;                                  // align 0
            float pcv = pcls[nn];
            float ps = 1.f / (1.f + __expf(-pcv));
            float i2 = iou * iou;
            float a = ps * i2 * i2 * i2;                               // ps^1 * iou^6
            maxu = fmaxf(maxu, a);
            if (iou > 0.1f && a > tv[9]) {
                // strict > keeps earlier (lower n) ahead on ties == top_k stability
                tv[9] = a; ti[9] = n;
#pragma unroll
                for (int j = 9; j > 0; --j) {
                    if (tv[j] > tv[j - 1]) {
                        float tf = tv[j]; tv[j] = tv[j - 1]; tv[j - 1] = tf;
                        int   tt = ti[j]; ti[j] = ti[j - 1]; ti[j - 1] = tt;
                    }
                }
            }
        }
    }

    __shared__ float sval[2560];
    __shared__ int   sidx[2560];
    __shared__ float rv[256];
    __shared__ int   ra[256];
    __shared__ int   rs[256];
    __shared__ float smax[256];
    __shared__ int   winners[10];
    __shared__ int   nwin;

#pragma unroll
    for (int j = 0; j < 10; j++) {
        sval[tid * 10 + j] = tv[j];
        sidx[tid * 10 + j] = ti[j];
    }
    smax[tid] = maxu;
    if (tid == 0) nwin = 0;
    __syncthreads();
    for (int s = 128; s > 0; s >>= 1) {
        if (tid < s) smax[tid] = fmaxf(smax[tid], smax[tid + s]);
        __syncthreads();
    }
    float denom = smax[0] + 1e-9f;

    // 10 rounds of block argmax (value desc, anchor idx asc) over 2560 candidates
    for (int r = 0; r < 10; r++) {
        float bv = -1.f; int ba = 0x7fffffff; int bs = -1;
#pragma unroll
        for (int j = 0; j < 10; j++) {
            int s0 = tid * 10 + j;
            float v = sval[s0]; int a0 = sidx[s0];
            if (v > bv || (v == bv && a0 < ba)) { bv = v; ba = a0; bs = s0; }
        }
        rv[tid] = bv; ra[tid] = ba; rs[tid] = bs;
        __syncthreads();
        for (int s = 128; s > 0; s >>= 1) {
            if (tid < s) {
                if (rv[tid + s] > rv[tid] ||
                    (rv[tid + s] == rv[tid] && ra[tid + s] < ra[tid])) {
                    rv[tid] = rv[tid + s]; ra[tid] = ra[tid + s]; rs[tid] = rs[tid + s];
                }
            }
            __syncthreads();
        }
        if (tid == 0 && rv[0] > 0.f) {
            float nv = rv[0] / denom;                 // normalized score in (0, 1]
            unsigned long long pk =
                ((unsigned long long)__float_as_uint(nv) << 32) |
                (unsigned long long)(31 - m);         // ties -> lower m wins (argmax-first)
            atomicMax(&best[(size_t)b * NANCHOR + ra[0]], pk);
            winners[nwin++] = ra[0];
            sval[rs[0]] = -1.f;
        }
        __syncthreads();
    }

    if (tid == 0 && nwin > 0) {
        unsigned int* list_cnt = (unsigned int*)(acc + 63);
        unsigned int base = atomicAdd(list_cnt, (unsigned int)nwin);
        for (int j = 0; j < nwin; j++)
            fglist[base + j] = make_uint2((unsigned int)(b * NANCHOR + winners[j]),
                                          (unsigned int)m);
    }
}

// Dense pass over the compact fg list. Entry processed only if its GT won the
// per-anchor argmax (best[bn] low bits == 31-m) -> exact dedupe semantics.
__global__ __launch_bounds__(256) void k_final(const float* __restrict__ p0,
                                               const float* __restrict__ p1,
                                               const float* __restrict__ p2,
                                               const float* __restrict__ px1,
                                               const float* __restrict__ py1,
                                               const float* __restrict__ px2,
                                               const float* __restrict__ py2,
                                               const float* __restrict__ gtb,
                                               const int* __restrict__ gtl,
                                               const unsigned long long* __restrict__ best,
                                               const uint2* __restrict__ fglist,
                                               float* __restrict__ acc) {
    __shared__ float sacc[BATCH][4];   // {box, dfl, clspos, numfg}
    int tid = threadIdx.x;
    if (tid < BATCH * 4) sacc[tid >> 2][tid & 3] = 0.f;
    __syncthreads();

    unsigned int cnt = *(const unsigned int*)(acc + 63);
    unsigned int i = blockIdx.x * 256 + tid;
    if (i < cnt) {
        uint2 e = fglist[i];
        int bn = (int)e.x, m = (int)e.y;
        unsigned long long pk = best[bn];
        if ((unsigned int)(pk & 0xffffffffull) == (unsigned int)(31 - m)) {
            int b = bn / NANCHOR, n = bn % NANCHOR;
            float score = __uint_as_float((unsigned int)(pk >> 32));
            const float* g = gtb + (size_t)(b * MGT + m) * 4;
            float g0 = g[0], g1 = g[1], g2 = g[2], g3 = g[3];
            int label = gtl[b * MGT + m];
            float c = ciou_f(px1[bn], py1[bn], px2[bn], py2[bn], g0, g1, g2, g3);

            AInfo ai = anchor_info(p0, p1, p2, b, n);
            float inv_st = 1.f / ai.st;           // exact (power of two)
            float t4[4] = { ai.apx - g0 * inv_st, ai.apy - g1 * inv_st,
                            g2 * inv_st - ai.apx, g3 * inv_st - ai.apy };
            float dfl = 0.f;
#pragma unroll
            for (int k = 0; k < 4; k++) {
                float t = fminf(fmaxf(t4[k], 0.f), 14.99f);   // box2dist clamp
                int left = (int)floorf(t);
                int right = (left + 1 < 15) ? left + 1 : 15;
                float wl = (float)right - t;
                float wr = t - (float)left;
                float v[16];
                float mx = -1e30f;
#pragma unroll
                for (int r = 0; r < 16; r++) {
                    v[r] = ai.ch0[(size_t)(k * 16 + r) * ai.hw];
                    mx = fmaxf(mx, v[r]);
                }
                float s = 0.f;
#pragma unroll
                for (int r = 0; r < 16; r++) s += __expf(v[r] - mx);
                float lse = mx + __logf(s);
                dfl += (lse - v[left]) * wl + (lse - v[right]) * wr;
            }
            float pcv = ai.ch0[(size_t)(64 + label) * ai.hw];

            atomicAdd(&sacc[b][0], 1.f - c);
            atomicAdd(&sacc[b][1], dfl);
            atomicAdd(&sacc[b][2], pcv * score);
            atomicAdd(&sacc[b][3], 1.f);
        }
    }
    __syncthreads();
    if (tid < BATCH * 4) {
        float v = sacc[tid >> 2][tid & 3];
        if (v != 0.f) atomicAdd(&acc[(tid >> 2) * 8 + 1 + (tid & 3)], v);
    }
}

__global__ void k_combine(const float* __restrict__ acc, float* __restrict__ out) {
    if (blockIdx.x == 0 && threadIdx.x == 0) {
        float total = 0.f;
        for (int b = 0; b < BATCH; b++) {
            float sp = 0.f;
            for (int j = 0; j < 8; j++) sp += acc[64 + b * 8 + j];
            float nfr = acc[b * 8 + 4];
            float has = nfr > 0.f ? 1.f : 0.f;
            float nf = fmaxf(nfr, 1.f);
            float box_l = acc[b * 8 + 1] / nf;
            float cls_l = (sp - acc[b * 8 + 3]) / (float)NANCHOR;
            float dfl_l = acc[b * 8 + 2] / (nf * 4.f);
            total += has * (7.5f * box_l + 0.5f * cls_l + 1.5f * dfl_l);
        }
        out[0] = total;
    }
}

extern "C" void kernel_launch(void* const* d_in, const int* in_sizes, int n_in,
                              void* d_out, int out_size, void* d_ws, size_t ws_size,
                              hipStream_t stream) {
    (void)in_sizes; (void)n_in; (void)out_size; (void)ws_size;
    const float* p0  = (const float*)d_in[0];
    const float* p1  = (const float*)d_in[1];
    const float* p2  = (const float*)d_in[2];
    const float* gtb = (const float*)d_in[3];
    const int*   gtl = (const int*)d_in[4];
    // d_in[5] = strides (8,16,32) — hardcoded in anchor_info

    const size_t BN = (size_t)BATCH * NANCHOR;
    char* ws = (char*)d_ws;
    unsigned long long* best = (unsigned long long*)ws;         // 2.15 MB
    float* px1 = (float*)(ws + BN * 8);                         // 1.075 MB each
    float* py1 = px1 + BN;
    float* px2 = py1 + BN;
    float* py2 = px2 + BN;
    float* acc = py2 + BN;                                      // 1 KB
    uint2* fglist = (uint2*)(acc + 256);                        // 20 KB

    k_init   <<<1, 256, 0, stream>>>(acc);
    k_decode <<<dim3(33, BATCH, 12), 256, 0, stream>>>(p0, p1, p2,
                (float4*)px1, (float4*)py1, (float4*)px2, (float4*)py2, best, acc);
    k_assign <<<BATCH * MGT, 256, 0, stream>>>(p0, p1, p2, px1, py1, px2, py2,
                                               gtb, gtl, best, acc, fglist);
    k_final  <<<(MAXFG + 255) / 256, 256, 0, stream>>>(p0, p1, p2, px1, py1, px2, py2,
                                                       gtb, gtl, best, fglist, acc);
    k_combine<<<1, 64, 0, stream>>>(acc, (float*)d_out);
}

// Round 7
// 277.990 us; speedup vs baseline: 1.0673x; 1.0673x over previous
//
#include <hip/hip_runtime.h>
#include <cstdint>

#define NANCHOR 33600
#define BATCH   8
#define MGT     32
#define NCLS    80
#define MAXFG   (BATCH * MGT * 10)   // 2560

// ---------------------------------------------------------------------------
// Anchor geometry: levels are [160x160 stride 8 | 80x80 stride 16 | 40x40 stride 32]
// p layout per level: [B, 144, H, W]; channel stride = H*W; anchor n = y*W + x.
// ---------------------------------------------------------------------------
struct AInfo {
    const float* ch0;   // &p_level[b][0][n]  (add c*hw for channel c)
    int   hw;
    float apx, apy, st;
};

__device__ __forceinline__ AInfo anchor_info(const float* p0, const float* p1,
                                             const float* p2, int b, int n) {
    AInfo r;
    if (n < 25600) {
        int nn = n;
        r.ch0 = p0 + (size_t)b * (144 * 25600) + nn;
        r.hw = 25600; r.st = 8.f;
        r.apx = (float)(nn % 160) + 0.5f;
        r.apy = (float)(nn / 160) + 0.5f;
    } else if (n < 32000) {
        int nn = n - 25600;
        r.ch0 = p1 + (size_t)b * (144 * 6400) + nn;
        r.hw = 6400; r.st = 16.f;
        r.apx = (float)(nn % 80) + 0.5f;
        r.apy = (float)(nn / 80) + 0.5f;
    } else {
        int nn = n - 32000;
        r.ch0 = p2 + (size_t)b * (144 * 1600) + nn;
        r.hw = 1600; r.st = 32.f;
        r.apx = (float)(nn % 40) + 0.5f;
        r.apy = (float)(nn / 40) + 0.5f;
    }
    return r;
}

__device__ __forceinline__ float ciou_f(float b1x1, float b1y1, float b1x2, float b1y2,
                                        float g1x, float g1y, float g2x, float g2y) {
    const float eps = 1e-7f;
    float w1 = b1x2 - b1x1, h1 = b1y2 - b1y1;
    float w2 = g2x - g1x,   h2 = g2y - g1y;
    float iw = fminf(b1x2, g2x) - fmaxf(b1x1, g1x);
    float ih = fminf(b1y2, g2y) - fmaxf(b1y1, g1y);
    float inter = fmaxf(iw, 0.f) * fmaxf(ih, 0.f);
    float uni = w1 * h1 + w2 * h2 - inter + eps;
    float iou = inter / uni;
    float cw = fmaxf(b1x2, g2x) - fminf(b1x1, g1x);
    float ch = fmaxf(b1y2, g2y) - fminf(b1y1, g1y);
    float c2 = cw * cw + ch * ch + eps;
    float dx = g1x + g2x - b1x1 - b1x2;
    float dy = g1y + g2y - b1y1 - b1y2;
    float rho2 = (dx * dx + dy * dy) * 0.25f;
    float t = atanf(w2 / (h2 + eps)) - atanf(w1 / (h1 + eps));
    float v = 0.40528473456935108577f * t * t;          // 4/pi^2
    float alpha = v / (v - iou + (1.f + eps));
    return iou - (rho2 / c2 + v * alpha);
}

__device__ __forceinline__ float4 max4(float4 a, float4 b) {
    return make_float4(fmaxf(a.x, b.x), fmaxf(a.y, b.y), fmaxf(a.z, b.z), fmaxf(a.w, b.w));
}
__device__ __forceinline__ float fast_splus(float x) {
    // softplus = max(x,0) + log(1 + e^{-|x|}) via native v_exp/v_log
    return fmaxf(x, 0.f) + __logf(1.f + __expf(-fabsf(x)));
}

// ---------------------------------------------------------------------------
// ws layout:
//   best : unsigned long long [B*N]   packed (score_bits<<32)|(31-m); 0 == no fg
//   pb SoA: px1,py1,px2,py2 float[B*N] each (decoded boxes, image units)
//   acc  : float [256]
//     [b*8+1]=box, +2=dfl, +3=clspos, +4=numfg; ((uint*)acc)[63]=fg-list count
//     [64 + b*8 + j] = softplus partial (j = 0..7)
//   fglist : uint2 [MAXFG]            (bn = b*NANCHOR+n, m)
// ---------------------------------------------------------------------------

__global__ void k_init(float* acc) {
    acc[threadIdx.x] = 0.f;     // 256 threads clear the whole acc region
}

// Single 1D grid, 256 threads/block, 1368 blocks:
//  blocks [0,528)    : DFL decode. bi -> (b = bi/66, role = (bi%66)/33,
//                      bx = bi%33). One thread = 4 consecutive anchors,
//                      2 box sides (role 0: sides 0,1 -> px1,py1 + clears
//                      best; role 1: sides 2,3 -> px2,py2). 32 unrolled
//                      independent float4 loads per thread (deep MLP).
//  blocks [528,1368) : softplus streaming. Each block owns one contiguous
//                      6400-float4 chunk of one (image,level) cls region;
//                      per image: 80 lvl0 + 20 lvl1 + 5 lvl2 = 105 blocks
//                      (exact division, branch-free fixed 25-iter loop).
__global__ __launch_bounds__(256) void k_decode(const float* __restrict__ p0,
                                                const float* __restrict__ p1,
                                                const float* __restrict__ p2,
                                                float4* __restrict__ px1,
                                                float4* __restrict__ py1,
                                                float4* __restrict__ px2,
                                                float4* __restrict__ py2,
                                                unsigned long long* __restrict__ best,
                                                float* __restrict__ acc) {
    int bi = blockIdx.x;
    int tid = threadIdx.x;

    if (bi >= 528) {
        int sbi = bi - 528;
        int b = sbi / 105;
        int r = sbi % 105;
        const float4* base;
        if (r < 80)
            base = (const float4*)(p0 + (size_t)b * 3686400 + 1638400) + r * 6400;
        else if (r < 100)
            base = (const float4*)(p1 + (size_t)b * 921600 + 409600) + (r - 80) * 6400;
        else
            base = (const float4*)(p2 + (size_t)b * 230400 + 102400) + (r - 100) * 6400;

        float sp = 0.f;
#pragma unroll
        for (int k = 0; k < 25; k++) {
            float4 x = base[k * 256 + tid];
            sp += fast_splus(x.x) + fast_splus(x.y) + fast_splus(x.z) + fast_splus(x.w);
        }
#pragma unroll
        for (int o = 32; o > 0; o >>= 1) sp += __shfl_down(sp, o, 64);
        if ((tid & 63) == 0) atomicAdd(&acc[64 + b * 8 + (sbi & 7)], sp);
        return;
    }

    int b = bi / 66;
    int rr = bi % 66;
    int role = rr / 33;                 // 0: sides {0,1}; 1: sides {2,3}
    int t = (rr % 33) * 256 + tid;
    if (t >= NANCHOR / 4) return;
    int n = t * 4;
    const float* ch0; int hw; float st, apx, apy;
    if (n < 25600) {
        ch0 = p0 + (size_t)b * (144 * 25600) + n;
        hw = 25600; st = 8.f;
        apx = (float)(n % 160) + 0.5f; apy = (float)(n / 160) + 0.5f;
    } else if (n < 32000) {
        int nn = n - 25600;
        ch0 = p1 + (size_t)b * (144 * 6400) + nn;
        hw = 6400; st = 16.f;
        apx = (float)(nn % 80) + 0.5f; apy = (float)(nn / 80) + 0.5f;
    } else {
        int nn = n - 32000;
        ch0 = p2 + (size_t)b * (144 * 1600) + nn;
        hw = 1600; st = 32.f;
        apx = (float)(nn % 40) + 0.5f; apy = (float)(nn / 40) + 0.5f;
    }

    int k0 = role * 2;                  // first side of this role
    float d[2][4];
#pragma unroll
    for (int kk = 0; kk < 2; kk++) {
        float4 v[16];
#pragma unroll
        for (int r = 0; r < 16; r++)
            v[r] = *(const float4*)(ch0 + (size_t)((k0 + kk) * 16 + r) * hw);
        float4 mx = v[0];
#pragma unroll
        for (int r = 1; r < 16; r++) mx = max4(mx, v[r]);
        float4 s  = make_float4(0.f, 0.f, 0.f, 0.f);
        float4 sw = make_float4(0.f, 0.f, 0.f, 0.f);
#pragma unroll
        for (int r = 0; r < 16; r++) {
            float fr = (float)r;
            float ex = __expf(v[r].x - mx.x);
            float ey = __expf(v[r].y - mx.y);
            float ez = __expf(v[r].z - mx.z);
            float ew = __expf(v[r].w - mx.w);
            s.x += ex; s.y += ey; s.z += ez; s.w += ew;
            sw.x += ex * fr; sw.y += ey * fr; sw.z += ez * fr; sw.w += ew * fr;
        }
        d[kk][0] = sw.x / s.x; d[kk][1] = sw.y / s.y;
        d[kk][2] = sw.z / s.z; d[kk][3] = sw.w / s.w;
    }

    size_t gi = ((size_t)b * NANCHOR + n) >> 2;
    if (role == 0) {
        px1[gi] = make_float4((apx + 0.f - d[0][0]) * st, (apx + 1.f - d[0][1]) * st,
                              (apx + 2.f - d[0][2]) * st, (apx + 3.f - d[0][3]) * st);
        py1[gi] = make_float4((apy - d[1][0]) * st, (apy - d[1][1]) * st,
                              (apy - d[1][2]) * st, (apy - d[1][3]) * st);
        // clear fg table for k_assign (runs strictly after this kernel)
        ulonglong2* bq = (ulonglong2*)(best + (size_t)b * NANCHOR + n);
        bq[0] = make_ulonglong2(0ull, 0ull);
        bq[1] = make_ulonglong2(0ull, 0ull);
    } else {
        px2[gi] = make_float4((apx + 0.f + d[0][0]) * st, (apx + 1.f + d[0][1]) * st,
                              (apx + 2.f + d[0][2]) * st, (apx + 3.f + d[0][3]) * st);
        py2[gi] = make_float4((apy + d[1][0]) * st, (apy + d[1][1]) * st,
                              (apy + d[1][2]) * st, (apy + d[1][3]) * st);
    }
}

// One block per (b, m). Scans only the per-level index window covering the GT
// box (conservative ±1; exact float in-gt test inside). Selection semantics
// are order-independent: (align value desc, anchor index asc).
// Selected anchors are appended to the compact fg list for k_final.
__global__ __launch_bounds__(256) void k_assign(const float* __restrict__ p0,
                                                const float* __restrict__ p1,
                                                const float* __restrict__ p2,
                                                const float* __restrict__ px1,
                                                const float* __restrict__ py1,
                                                const float* __restrict__ px2,
                                                const float* __restrict__ py2,
                                                const float* __restrict__ gtb,
                                                const int* __restrict__ gtl,
                                                unsigned long long* __restrict__ best,
                                                float* __restrict__ acc,
                                                uint2* __restrict__ fglist) {
    int bm = blockIdx.x;          // 256 blocks: one per (b, m)
    int b = bm >> 5, m = bm & 31;
    const float* g = gtb + (size_t)(b * MGT + m) * 4;
    float g0 = g[0], g1 = g[1], g2 = g[2], g3 = g[3];
    int label = gtl[b * MGT + m];
    int tid = threadIdx.x;

    float tv[10];
    int   ti[10];
#pragma unroll
    for (int j = 0; j < 10; j++) { tv[j] = -1.f; ti[j] = 0x7fffffff; }
    float maxu = 0.f;   // max over UNMASKED align (pre iou>0.1 filter)

    const int   LW[3]   = {160, 80, 40};
    const int   LOFF[3] = {0, 25600, 32000};
    const float LST[3]  = {8.f, 16.f, 32.f};

    for (int l = 0; l < 3; l++) {
        float st = LST[l];
        int W = LW[l];
        float inv_st = 1.f / st;
        int ix0 = max(0,     (int)floorf(g0 * inv_st - 0.5f) - 1);
        int ix1 = min(W - 1, (int)ceilf (g2 * inv_st - 0.5f) + 1);
        int iy0 = max(0,     (int)floorf(g1 * inv_st - 0.5f) - 1);
        int iy1 = min(W - 1, (int)ceilf (g3 * inv_st - 0.5f) + 1);
        int nx = ix1 - ix0 + 1, ny = iy1 - iy0 + 1;
        if (nx <= 0 || ny <= 0) continue;
        int cnt = nx * ny;
        const float* lp = (l == 0) ? p0 : (l == 1) ? p1 : p2;
        int hw = W * W;
        const float* ch0 = lp + (size_t)b * 144 * hw;
        const float* pcls = ch0 + (size_t)(64 + label) * hw;

        for (int idx = tid; idx < cnt; idx += 256) {
            int iy = iy0 + idx / nx;
            int ix = ix0 + idx % nx;
            float ax = ((float)ix + 0.5f) * st;
            float ay = ((float)iy + 0.5f) * st;
            if (ax < g0 || ax > g2 || ay < g1 || ay > g3) continue;   // exact in_gt
            int nn = iy * W + ix;
            int n = LOFF[l] + nn;
            size_t bn = (size_t)b * NANCHOR + n;
            float c = ciou_f(px1[bn], py1[bn], px2[bn], py2[bn], g0, g1, g2, g3);
            float iou = fmaxf(c, 0.f);
            if (iou <= 0.f) continue;                                  // align 0
            float pcv = pcls[nn];
            float ps = 1.f / (1.f + __expf(-pcv));
            float i2 = iou * iou;
            float a = ps * i2 * i2 * i2;                               // ps^1 * iou^6
            maxu = fmaxf(maxu, a);
            if (iou > 0.1f && a > tv[9]) {
                // strict > keeps earlier (lower n) ahead on ties == top_k stability
                tv[9] = a; ti[9] = n;
#pragma unroll
                for (int j = 9; j > 0; --j) {
                    if (tv[j] > tv[j - 1]) {
                        float tf = tv[j]; tv[j] = tv[j - 1]; tv[j - 1] = tf;
                        int   tt = ti[j]; ti[j] = ti[j - 1]; ti[j - 1] = tt;
                    }
                }
            }
        }
    }

    __shared__ float sval[2560];
    __shared__ int   sidx[2560];
    __shared__ float rv[256];
    __shared__ int   ra[256];
    __shared__ int   rs[256];
    __shared__ float smax[256];
    __shared__ int   winners[10];
    __shared__ int   nwin;

#pragma unroll
    for (int j = 0; j < 10; j++) {
        sval[tid * 10 + j] = tv[j];
        sidx[tid * 10 + j] = ti[j];
    }
    smax[tid] = maxu;
    if (tid == 0) nwin = 0;
    __syncthreads();
    for (int s = 128; s > 0; s >>= 1) {
        if (tid < s) smax[tid] = fmaxf(smax[tid], smax[tid + s]);
        __syncthreads();
    }
    float denom = smax[0] + 1e-9f;

    // 10 rounds of block argmax (value desc, anchor idx asc) over 2560 candidates
    for (int r = 0; r < 10; r++) {
        float bv = -1.f; int ba = 0x7fffffff; int bs = -1;
#pragma unroll
        for (int j = 0; j < 10; j++) {
            int s0 = tid * 10 + j;
            float v = sval[s0]; int a0 = sidx[s0];
            if (v > bv || (v == bv && a0 < ba)) { bv = v; ba = a0; bs = s0; }
        }
        rv[tid] = bv; ra[tid] = ba; rs[tid] = bs;
        __syncthreads();
        for (int s = 128; s > 0; s >>= 1) {
            if (tid < s) {
                if (rv[tid + s] > rv[tid] ||
                    (rv[tid + s] == rv[tid] && ra[tid + s] < ra[tid])) {
                    rv[tid] = rv[tid + s]; ra[tid] = ra[tid + s]; rs[tid] = rs[tid + s];
                }
            }
            __syncthreads();
        }
        if (tid == 0 && rv[0] > 0.f) {
            float nv = rv[0] / denom;                 // normalized score in (0, 1]
            unsigned long long pk =
                ((unsigned long long)__float_as_uint(nv) << 32) |
                (unsigned long long)(31 - m);         // ties -> lower m wins (argmax-first)
            atomicMax(&best[(size_t)b * NANCHOR + ra[0]], pk);
            winners[nwin++] = ra[0];
            sval[rs[0]] = -1.f;
        }
        __syncthreads();
    }

    if (tid == 0 && nwin > 0) {
        unsigned int* list_cnt = (unsigned int*)(acc + 63);
        unsigned int base = atomicAdd(list_cnt, (unsigned int)nwin);
        for (int j = 0; j < nwin; j++)
            fglist[base + j] = make_uint2((unsigned int)(b * NANCHOR + winners[j]),
                                          (unsigned int)m);
    }
}

// Dense pass over the compact fg list. Entry processed only if its GT won the
// per-anchor argmax (best[bn] low bits == 31-m) -> exact dedupe semantics.
__global__ __launch_bounds__(256) void k_final(const float* __restrict__ p0,
                                               const float* __restrict__ p1,
                                               const float* __restrict__ p2,
                                               const float* __restrict__ px1,
                                               const float* __restrict__ py1,
                                               const float* __restrict__ px2,
                                               const float* __restrict__ py2,
                                               const float* __restrict__ gtb,
                                               const int* __restrict__ gtl,
                                               const unsigned long long* __restrict__ best,
                                               const uint2* __restrict__ fglist,
                                               float* __restrict__ acc) {
    __shared__ float sacc[BATCH][4];   // {box, dfl, clspos, numfg}
    int tid = threadIdx.x;
    if (tid < BATCH * 4) sacc[tid >> 2][tid & 3] = 0.f;
    __syncthreads();

    unsigned int cnt = *(const unsigned int*)(acc + 63);
    unsigned int i = blockIdx.x * 256 + tid;
    if (i < cnt) {
        uint2 e = fglist[i];
        int bn = (int)e.x, m = (int)e.y;
        unsigned long long pk = best[bn];
        if ((unsigned int)(pk & 0xffffffffull) == (unsigned int)(31 - m)) {
            int b = bn / NANCHOR, n = bn % NANCHOR;
            float score = __uint_as_float((unsigned int)(pk >> 32));
            const float* g = gtb + (size_t)(b * MGT + m) * 4;
            float g0 = g[0], g1 = g[1], g2 = g[2], g3 = g[3];
            int label = gtl[b * MGT + m];
            float c = ciou_f(px1[bn], py1[bn], px2[bn], py2[bn], g0, g1, g2, g3);

            AInfo ai = anchor_info(p0, p1, p2, b, n);
            float inv_st = 1.f / ai.st;           // exact (power of two)
            float t4[4] = { ai.apx - g0 * inv_st, ai.apy - g1 * inv_st,
                            g2 * inv_st - ai.apx, g3 * inv_st - ai.apy };
            float dfl = 0.f;
#pragma unroll
            for (int k = 0; k < 4; k++) {
                float t = fminf(fmaxf(t4[k], 0.f), 14.99f);   // box2dist clamp
                int left = (int)floorf(t);
                int right = (left + 1 < 15) ? left + 1 : 15;
                float wl = (float)right - t;
                float wr = t - (float)left;
                float v[16];
                float mx = -1e30f;
#pragma unroll
                for (int r = 0; r < 16; r++) {
                    v[r] = ai.ch0[(size_t)(k * 16 + r) * ai.hw];
                    mx = fmaxf(mx, v[r]);
                }
                float s = 0.f;
#pragma unroll
                for (int r = 0; r < 16; r++) s += __expf(v[r] - mx);
                float lse = mx + __logf(s);
                dfl += (lse - v[left]) * wl + (lse - v[right]) * wr;
            }
            float pcv = ai.ch0[(size_t)(64 + label) * ai.hw];

            atomicAdd(&sacc[b][0], 1.f - c);
            atomicAdd(&sacc[b][1], dfl);
            atomicAdd(&sacc[b][2], pcv * score);
            atomicAdd(&sacc[b][3], 1.f);
        }
    }
    __syncthreads();
    if (tid < BATCH * 4) {
        float v = sacc[tid >> 2][tid & 3];
        if (v != 0.f) atomicAdd(&acc[(tid >> 2) * 8 + 1 + (tid & 3)], v);
    }
}

__global__ void k_combine(const float* __restrict__ acc, float* __restrict__ out) {
    if (blockIdx.x == 0 && threadIdx.x == 0) {
        float total = 0.f;
        for (int b = 0; b < BATCH; b++) {
            float sp = 0.f;
            for (int j = 0; j < 8; j++) sp += acc[64 + b * 8 + j];
            float nfr = acc[b * 8 + 4];
            float has = nfr > 0.f ? 1.f : 0.f;
            float nf = fmaxf(nfr, 1.f);
            float box_l = acc[b * 8 + 1] / nf;
            float cls_l = (sp - acc[b * 8 + 3]) / (float)NANCHOR;
            float dfl_l = acc[b * 8 + 2] / (nf * 4.f);
            total += has * (7.5f * box_l + 0.5f * cls_l + 1.5f * dfl_l);
        }
        out[0] = total;
    }
}

extern "C" void kernel_launch(void* const* d_in, const int* in_sizes, int n_in,
                              void* d_out, int out_size, void* d_ws, size_t ws_size,
                              hipStream_t stream) {
    (void)in_sizes; (void)n_in; (void)out_size; (void)ws_size;
    const float* p0  = (const float*)d_in[0];
    const float* p1  = (const float*)d_in[1];
    const float* p2  = (const float*)d_in[2];
    const float* gtb = (const float*)d_in[3];
    const int*   gtl = (const int*)d_in[4];
    // d_in[5] = strides (8,16,32) — hardcoded in anchor_info

    const size_t BN = (size_t)BATCH * NANCHOR;
    char* ws = (char*)d_ws;
    unsigned long long* best = (unsigned long long*)ws;         // 2.15 MB
    float* px1 = (float*)(ws + BN * 8);                         // 1.075 MB each
    float* py1 = px1 + BN;
    float* px2 = py1 + BN;
    float* py2 = px2 + BN;
    float* acc = py2 + BN;                                      // 1 KB
    uint2* fglist = (uint2*)(acc + 256);                        // 20 KB

    k_init   <<<1, 256, 0, stream>>>(acc);
    k_decode <<<528 + 840, 256, 0, stream>>>(p0, p1, p2,
                (float4*)px1, (float4*)py1, (float4*)px2, (float4*)py2, best, acc);
    k_assign <<<BATCH * MGT, 256, 0, stream>>>(p0, p1, p2, px1, py1, px2, py2,
                                               gtb, gtl, best, acc, fglist);
    k_final  <<<(MAXFG + 255) / 256, 256, 0, stream>>>(p0, p1, p2, px1, py1, px2, py2,
                                                       gtb, gtl, best, fglist, acc);
    k_combine<<<1, 64, 0, stream>>>(acc, (float*)d_out);
}

// Round 8
// 263.400 us; speedup vs baseline: 1.1264x; 1.0554x over previous
//
#include <hip/hip_runtime.h>
#include <cstdint>

#define NANCHOR 33600
#define BATCH   8
#define MGT     32
#define NCLS    80
#define MAXFG   (BATCH * MGT * 10)   // 2560

// ---------------------------------------------------------------------------
// Anchor geometry: levels are [160x160 stride 8 | 80x80 stride 16 | 40x40 stride 32]
// p layout per level: [B, 144, H, W]; channel stride = H*W; anchor n = y*W + x.
// ---------------------------------------------------------------------------
struct AInfo {
    const float* ch0;   // &p_level[b][0][n]  (add c*hw for channel c)
    int   hw;
    float apx, apy, st;
};

__device__ __forceinline__ AInfo anchor_info(const float* p0, const float* p1,
                                             const float* p2, int b, int n) {
    AInfo r;
    if (n < 25600) {
        int nn = n;
        r.ch0 = p0 + (size_t)b * (144 * 25600) + nn;
        r.hw = 25600; r.st = 8.f;
        r.apx = (float)(nn % 160) + 0.5f;
        r.apy = (float)(nn / 160) + 0.5f;
    } else if (n < 32000) {
        int nn = n - 25600;
        r.ch0 = p1 + (size_t)b * (144 * 6400) + nn;
        r.hw = 6400; r.st = 16.f;
        r.apx = (float)(nn % 80) + 0.5f;
        r.apy = (float)(nn / 80) + 0.5f;
    } else {
        int nn = n - 32000;
        r.ch0 = p2 + (size_t)b * (144 * 1600) + nn;
        r.hw = 1600; r.st = 32.f;
        r.apx = (float)(nn % 40) + 0.5f;
        r.apy = (float)(nn / 40) + 0.5f;
    }
    return r;
}

__device__ __forceinline__ float ciou_f(float b1x1, float b1y1, float b1x2, float b1y2,
                                        float g1x, float g1y, float g2x, float g2y) {
    const float eps = 1e-7f;
    float w1 = b1x2 - b1x1, h1 = b1y2 - b1y1;
    float w2 = g2x - g1x,   h2 = g2y - g1y;
    float iw = fminf(b1x2, g2x) - fmaxf(b1x1, g1x);
    float ih = fminf(b1y2, g2y) - fmaxf(b1y1, g1y);
    float inter = fmaxf(iw, 0.f) * fmaxf(ih, 0.f);
    float uni = w1 * h1 + w2 * h2 - inter + eps;
    float iou = inter / uni;
    float cw = fmaxf(b1x2, g2x) - fminf(b1x1, g1x);
    float ch = fmaxf(b1y2, g2y) - fminf(b1y1, g1y);
    float c2 = cw * cw + ch * ch + eps;
    float dx = g1x + g2x - b1x1 - b1x2;
    float dy = g1y + g2y - b1y1 - b1y2;
    float rho2 = (dx * dx + dy * dy) * 0.25f;
    float t = atanf(w2 / (h2 + eps)) - atanf(w1 / (h1 + eps));
    float v = 0.40528473456935108577f * t * t;          // 4/pi^2
    float alpha = v / (v - iou + (1.f + eps));
    return iou - (rho2 / c2 + v * alpha);
}

__device__ __forceinline__ float fast_splus(float x) {
    // softplus = max(x,0) + log(1 + e^{-|x|}) via native v_exp/v_log
    return fmaxf(x, 0.f) + __logf(1.f + __expf(-fabsf(x)));
}

// async global->LDS, 16 B per lane. LDS dest = wave-uniform base + lane*16.
__device__ __forceinline__ void load16(const float* g, float* l) {
    __builtin_amdgcn_global_load_lds(
        (__attribute__((address_space(1))) void*)(g),
        (__attribute__((address_space(3))) void*)(l), 16, 0, 0);
}

// ---------------------------------------------------------------------------
// ws layout:
//   best : unsigned long long [B*N]   packed (score_bits<<32)|(31-m); 0 == no fg
//   pb SoA: px1,py1,px2,py2 float[B*N] each (decoded boxes, image units)
//   acc  : float [256]
//     [b*8+1]=box, +2=dfl, +3=clspos, +4=numfg; ((uint*)acc)[63]=fg-list count
//     [64 + b*8 + j] = softplus partial (j = 0..7)
//   fglist : uint2 [MAXFG]            (bn = b*NANCHOR+n, m)
// ---------------------------------------------------------------------------

__global__ void k_init(float* acc) {
    acc[threadIdx.x] = 0.f;     // 256 threads clear the whole acc region
}

// Single 1D grid of 6344 blocks x 256 threads, 32 KB LDS each.
//  blocks [0,2144)    : DFL. bi -> (b = bi/268; s = (bi%268)/67; ci = bi%67).
//      ci<50: lvl0 chunk ci; ci<63: lvl1 chunk ci-50; else lvl2 chunk ci-63.
//      Stage 16 channels x 512 floats (2 KB/ch) via 32 async 1KB wave-loads,
//      then per-thread softmax for anchors (c*512+tid, c*512+256+tid).
//      Partial chunks bleed into the next channel (valid memory, results
//      discarded by the a<hw guard). Side 0 also clears best[].
//  blocks [2144,6344) : softplus. sbi=bi-2144 -> b=sbi/525, r=sbi%525.
//      r<400: lvl0 seg r*20; r<500: lvl1 (r-400)*20; else lvl2 (r-500)*20.
//      20 segs of 256 floats staged (exact tiling of each cls region),
//      5 float4/thread from LDS, block-reduced single atomic.
__global__ __launch_bounds__(256) void k_decode(const float* __restrict__ p0,
                                                const float* __restrict__ p1,
                                                const float* __restrict__ p2,
                                                float* __restrict__ px1,
                                                float* __restrict__ py1,
                                                float* __restrict__ px2,
                                                float* __restrict__ py2,
                                                unsigned long long* __restrict__ best,
                                                float* __restrict__ acc) {
    __shared__ float lds[8192];   // 32 KB
    int bi = blockIdx.x;
    int tid = threadIdx.x;
    int w = tid >> 6, lane = tid & 63;

    if (bi < 2144) {
        int b = bi / 268;
        int rem = bi % 268;
        int s = rem / 67;
        int ci = rem % 67;
        const float* lp; int hw, loff, W, c; float st;
        if (ci < 50)      { lp = p0 + (size_t)b * 3686400; hw = 25600; loff = 0;
                            W = 160; st = 8.f;  c = ci; }
        else if (ci < 63) { lp = p1 + (size_t)b * 921600;  hw = 6400;  loff = 25600;
                            W = 80;  st = 16.f; c = ci - 50; }
        else              { lp = p2 + (size_t)b * 230400;  hw = 1600;  loff = 32000;
                            W = 40;  st = 32.f; c = ci - 63; }
        const float* side = lp + (size_t)(s * 16) * hw;

#pragma unroll
        for (int i = 0; i < 8; i++) {
            int seg = w * 8 + i;           // wave-uniform
            int r = seg >> 1, h = seg & 1;
            const float* g = side + (size_t)r * hw + c * 512 + h * 256 + lane * 4;
            load16(g, lds + seg * 256);
        }
        __syncthreads();                    // drains vmcnt before barrier

        float* plane = (s == 0) ? px1 : (s == 1) ? py1 : (s == 2) ? px2 : py2;
#pragma unroll
        for (int j = 0; j < 2; j++) {
            int a = c * 512 + j * 256 + tid;
            if (a >= hw) continue;
            float v[16];
            float mx = -1e30f;
#pragma unroll
            for (int r = 0; r < 16; r++) {
                v[r] = lds[r * 512 + j * 256 + tid];
                mx = fmaxf(mx, v[r]);
            }
            float sum = 0.f, sw = 0.f;
#pragma unroll
            for (int r = 0; r < 16; r++) {
                float e = __expf(v[r] - mx);
                sum += e;
                sw += e * (float)r;
            }
            float d = sw / sum;
            float ap = (s & 1) ? (float)(a / W) + 0.5f : (float)(a % W) + 0.5f;
            float val = (s < 2) ? (ap - d) * st : (ap + d) * st;
            size_t bn = (size_t)b * NANCHOR + loff + a;
            plane[bn] = val;
            if (s == 0) best[bn] = 0ull;   // clear fg table for k_assign
        }
        return;
    }

    // ---- softplus streaming ----
    int sbi = bi - 2144;
    int b = sbi / 525;
    int r = sbi % 525;
    const float* base; int segbase;
    if (r < 400)      { base = p0 + (size_t)b * 3686400 + 1638400; segbase = r * 20; }
    else if (r < 500) { base = p1 + (size_t)b * 921600  + 409600;  segbase = (r - 400) * 20; }
    else              { base = p2 + (size_t)b * 230400  + 102400;  segbase = (r - 500) * 20; }

#pragma unroll
    for (int i = 0; i < 5; i++) {
        int seg = w * 5 + i;               // wave-uniform
        const float* g = base + (size_t)(segbase + seg) * 256 + lane * 4;
        load16(g, lds + seg * 256);
    }
    __syncthreads();

    const float4* l4 = (const float4*)lds;
    float sp = 0.f;
#pragma unroll
    for (int k = 0; k < 5; k++) {
        float4 x = l4[k * 256 + tid];
        sp += fast_splus(x.x) + fast_splus(x.y) + fast_splus(x.z) + fast_splus(x.w);
    }
#pragma unroll
    for (int o = 32; o > 0; o >>= 1) sp += __shfl_down(sp, o, 64);
    __syncthreads();                        // all LDS reads done; reuse lds[0..3]
    if (lane == 0) lds[w] = sp;
    __syncthreads();
    if (tid == 0)
        atomicAdd(&acc[64 + b * 8 + (sbi & 7)], lds[0] + lds[1] + lds[2] + lds[3]);
}

// One block per (b, m). Scans only the per-level index window covering the GT
// box (conservative ±1; exact float in-gt test inside). Selection semantics
// are order-independent: (align value desc, anchor index asc).
// Selected anchors are appended to the compact fg list for k_final.
__global__ __launch_bounds__(256) void k_assign(const float* __restrict__ p0,
                                                const float* __restrict__ p1,
                                                const float* __restrict__ p2,
                                                const float* __restrict__ px1,
                                                const float* __restrict__ py1,
                                                const float* __restrict__ px2,
                                                const float* __restrict__ py2,
                                                const float* __restrict__ gtb,
                                                const int* __restrict__ gtl,
                                                unsigned long long* __restrict__ best,
                                                float* __restrict__ acc,
                                                uint2* __restrict__ fglist) {
    int bm = blockIdx.x;          // 256 blocks: one per (b, m)
    int b = bm >> 5, m = bm & 31;
    const float* g = gtb + (size_t)(b * MGT + m) * 4;
    float g0 = g[0], g1 = g[1], g2 = g[2], g3 = g[3];
    int label = gtl[b * MGT + m];
    int tid = threadIdx.x;

    float tv[10];
    int   ti[10];
#pragma unroll
    for (int j = 0; j < 10; j++) { tv[j] = -1.f; ti[j] = 0x7fffffff; }
    float maxu = 0.f;   // max over UNMASKED align (pre iou>0.1 filter)

    const int   LW[3]   = {160, 80, 40};
    const int   LOFF[3] = {0, 25600, 32000};
    const float LST[3]  = {8.f, 16.f, 32.f};

    for (int l = 0; l < 3; l++) {
        float st = LST[l];
        int W = LW[l];
        float inv_st = 1.f / st;
        int ix0 = max(0,     (int)floorf(g0 * inv_st - 0.5f) - 1);
        int ix1 = min(W - 1, (int)ceilf (g2 * inv_st - 0.5f) + 1);
        int iy0 = max(0,     (int)floorf(g1 * inv_st - 0.5f) - 1);
        int iy1 = min(W - 1, (int)ceilf (g3 * inv_st - 0.5f) + 1);
        int nx = ix1 - ix0 + 1, ny = iy1 - iy0 + 1;
        if (nx <= 0 || ny <= 0) continue;
        int cnt = nx * ny;
        const float* lp = (l == 0) ? p0 : (l == 1) ? p1 : p2;
        int hw = W * W;
        const float* ch0 = lp + (size_t)b * 144 * hw;
        const float* pcls = ch0 + (size_t)(64 + label) * hw;

        for (int idx = tid; idx < cnt; idx += 256) {
            int iy = iy0 + idx / nx;
            int ix = ix0 + idx % nx;
            float ax = ((float)ix + 0.5f) * st;
            float ay = ((float)iy + 0.5f) * st;
            if (ax < g0 || ax > g2 || ay < g1 || ay > g3) continue;   // exact in_gt
            int nn = iy * W + ix;
            int n = LOFF[l] + nn;
            size_t bn = (size_t)b * NANCHOR + n;
            float c = ciou_f(px1[bn], py1[bn], px2[bn], py2[bn], g0, g1, g2, g3);
            float iou = fmaxf(c, 0.f);
            if (iou <= 0.f) continue;                                  // align 0
            float pcv = pcls[nn];
            float ps = 1.f / (1.f + __expf(-pcv));
            float i2 = iou * iou;
            float a = ps * i2 * i2 * i2;                               // ps^1 * iou^6
            maxu = fmaxf(maxu, a);
            if (iou > 0.1f && a > tv[9]) {
                // strict > keeps earlier (lower n) ahead on ties == top_k stability
                tv[9] = a; ti[9] = n;
#pragma unroll
                for (int j = 9; j > 0; --j) {
                    if (tv[j] > tv[j - 1]) {
                        float tf = tv[j]; tv[j] = tv[j - 1]; tv[j - 1] = tf;
                        int   tt = ti[j]; ti[j] = ti[j - 1]; ti[j - 1] = tt;
                    }
                }
            }
        }
    }

    __shared__ float sval[2560];
    __shared__ int   sidx[2560];
    __shared__ float rv[256];
    __shared__ int   ra[256];
    __shared__ int   rs[256];
    __shared__ float smax[256];
    __shared__ int   winners[10];
    __shared__ int   nwin;

#pragma unroll
    for (int j = 0; j < 10; j++) {
        sval[tid * 10 + j] = tv[j];
        sidx[tid * 10 + j] = ti[j];
    }
    smax[tid] = maxu;
    if (tid == 0) nwin = 0;
    __syncthreads();
    for (int s = 128; s > 0; s >>= 1) {
        if (tid < s) smax[tid] = fmaxf(smax[tid], smax[tid + s]);
        __syncthreads();
    }
    float denom = smax[0] + 1e-9f;

    // 10 rounds of block argmax (value desc, anchor idx asc) over 2560 candidates
    for (int r = 0; r < 10; r++) {
        float bv = -1.f; int ba = 0x7fffffff; int bs = -1;
#pragma unroll
        for (int j = 0; j < 10; j++) {
            int s0 = tid * 10 + j;
            float v = sval[s0]; int a0 = sidx[s0];
            if (v > bv || (v == bv && a0 < ba)) { bv = v; ba = a0; bs = s0; }
        }
        rv[tid] = bv; ra[tid] = ba; rs[tid] = bs;
        __syncthreads();
        for (int s = 128; s > 0; s >>= 1) {
            if (tid < s) {
                if (rv[tid + s] > rv[tid] ||
                    (rv[tid + s] == rv[tid] && ra[tid + s] < ra[tid])) {
                    rv[tid] = rv[tid + s]; ra[tid] = ra[tid + s]; rs[tid] = rs[tid + s];
                }
            }
            __syncthreads();
        }
        if (tid == 0 && rv[0] > 0.f) {
            float nv = rv[0] / denom;                 // normalized score in (0, 1]
            unsigned long long pk =
                ((unsigned long long)__float_as_uint(nv) << 32) |
                (unsigned long long)(31 - m);         // ties -> lower m wins (argmax-first)
            atomicMax(&best[(size_t)b * NANCHOR + ra[0]], pk);
            winners[nwin++] = ra[0];
            sval[rs[0]] = -1.f;
        }
        __syncthreads();
    }

    if (tid == 0 && nwin > 0) {
        unsigned int* list_cnt = (unsigned int*)(acc + 63);
        unsigned int base = atomicAdd(list_cnt, (unsigned int)nwin);
        for (int j = 0; j < nwin; j++)
            fglist[base + j] = make_uint2((unsigned int)(b * NANCHOR + winners[j]),
                                          (unsigned int)m);
    }
}

// Dense pass over the compact fg list. Entry processed only if its GT won the
// per-anchor argmax (best[bn] low bits == 31-m) -> exact dedupe semantics.
__global__ __launch_bounds__(256) void k_final(const float* __restrict__ p0,
                                               const float* __restrict__ p1,
                                               const float* __restrict__ p2,
                                               const float* __restrict__ px1,
                                               const float* __restrict__ py1,
                                               const float* __restrict__ px2,
                                               const float* __restrict__ py2,
                                               const float* __restrict__ gtb,
                                               const int* __restrict__ gtl,
                                               const unsigned long long* __restrict__ best,
                                               const uint2* __restrict__ fglist,
                                               float* __restrict__ acc) {
    __shared__ float sacc[BATCH][4];   // {box, dfl, clspos, numfg}
    int tid = threadIdx.x;
    if (tid < BATCH * 4) sacc[tid >> 2][tid & 3] = 0.f;
    __syncthreads();

    unsigned int cnt = *(const unsigned int*)(acc + 63);
    unsigned int i = blockIdx.x * 256 + tid;
    if (i < cnt) {
        uint2 e = fglist[i];
        int bn = (int)e.x, m = (int)e.y;
        unsigned long long pk = best[bn];
        if ((unsigned int)(pk & 0xffffffffull) == (unsigned int)(31 - m)) {
            int b = bn / NANCHOR, n = bn % NANCHOR;
            float score = __uint_as_float((unsigned int)(pk >> 32));
            const float* g = gtb + (size_t)(b * MGT + m) * 4;
            float g0 = g[0], g1 = g[1], g2 = g[2], g3 = g[3];
            int label = gtl[b * MGT + m];
            float c = ciou_f(px1[bn], py1[bn], px2[bn], py2[bn], g0, g1, g2, g3);

            AInfo ai = anchor_info(p0, p1, p2, b, n);
            float inv_st = 1.f / ai.st;           // exact (power of two)
            float t4[4] = { ai.apx - g0 * inv_st, ai.apy - g1 * inv_st,
                            g2 * inv_st - ai.apx, g3 * inv_st - ai.apy };
            float dfl = 0.f;
#pragma unroll
            for (int k = 0; k < 4; k++) {
                float t = fminf(fmaxf(t4[k], 0.f), 14.99f);   // box2dist clamp
                int left = (int)floorf(t);
                int right = (left + 1 < 15) ? left + 1 : 15;
                float wl = (float)right - t;
                float wr = t - (float)left;
                float v[16];
                float mx = -1e30f;
#pragma unroll
                for (int r = 0; r < 16; r++) {
                    v[r] = ai.ch0[(size_t)(k * 16 + r) * ai.hw];
                    mx = fmaxf(mx, v[r]);
                }
                float s = 0.f;
#pragma unroll
                for (int r = 0; r < 16; r++) s += __expf(v[r] - mx);
                float lse = mx + __logf(s);
                dfl += (lse - v[left]) * wl + (lse - v[right]) * wr;
            }
            float pcv = ai.ch0[(size_t)(64 + label) * ai.hw];

            atomicAdd(&sacc[b][0], 1.f - c);
            atomicAdd(&sacc[b][1], dfl);
            atomicAdd(&sacc[b][2], pcv * score);
            atomicAdd(&sacc[b][3], 1.f);
        }
    }
    __syncthreads();
    if (tid < BATCH * 4) {
        float v = sacc[tid >> 2][tid & 3];
        if (v != 0.f) atomicAdd(&acc[(tid >> 2) * 8 + 1 + (tid & 3)], v);
    }
}

__global__ void k_combine(const float* __restrict__ acc, float* __restrict__ out) {
    if (blockIdx.x == 0 && threadIdx.x == 0) {
        float total = 0.f;
        for (int b = 0; b < BATCH; b++) {
            float sp = 0.f;
            for (int j = 0; j < 8; j++) sp += acc[64 + b * 8 + j];
            float nfr = acc[b * 8 + 4];
            float has = nfr > 0.f ? 1.f : 0.f;
            float nf = fmaxf(nfr, 1.f);
            float box_l = acc[b * 8 + 1] / nf;
            float cls_l = (sp - acc[b * 8 + 3]) / (float)NANCHOR;
            float dfl_l = acc[b * 8 + 2] / (nf * 4.f);
            total += has * (7.5f * box_l + 0.5f * cls_l + 1.5f * dfl_l);
        }
        out[0] = total;
    }
}

extern "C" void kernel_launch(void* const* d_in, const int* in_sizes, int n_in,
                              void* d_out, int out_size, void* d_ws, size_t ws_size,
                              hipStream_t stream) {
    (void)in_sizes; (void)n_in; (void)out_size; (void)ws_size;
    const float* p0  = (const float*)d_in[0];
    const float* p1  = (const float*)d_in[1];
    const float* p2  = (const float*)d_in[2];
    const float* gtb = (const float*)d_in[3];
    const int*   gtl = (const int*)d_in[4];
    // d_in[5] = strides (8,16,32) — hardcoded in anchor_info

    const size_t BN = (size_t)BATCH * NANCHOR;
    char* ws = (char*)d_ws;
    unsigned long long* best = (unsigned long long*)ws;         // 2.15 MB
    float* px1 = (float*)(ws + BN * 8);                         // 1.075 MB each
    float* py1 = px1 + BN;
    float* px2 = py1 + BN;
    float* py2 = px2 + BN;
    float* acc = py2 + BN;                                      // 1 KB
    uint2* fglist = (uint2*)(acc + 256);                        // 20 KB

    k_init   <<<1, 256, 0, stream>>>(acc);
    k_decode <<<2144 + 4200, 256, 0, stream>>>(p0, p1, p2, px1, py1, px2, py2, best, acc);
    k_assign <<<BATCH * MGT, 256, 0, stream>>>(p0, p1, p2, px1, py1, px2, py2,
                                               gtb, gtl, best, acc, fglist);
    k_final  <<<(MAXFG + 255) / 256, 256, 0, stream>>>(p0, p1, p2, px1, py1, px2, py2,
                                                       gtb, gtl, best, fglist, acc);
    k_combine<<<1, 64, 0, stream>>>(acc, (float*)d_out);
}